// Round 21
// baseline (316.718 us; speedup 1.0000x reference)
//
#include <hip/hip_runtime.h>
#include <math.h>

#define BATCH 8
#define NPTS  4096
#define NBR   16
#define MTOT  (BATCH * NPTS)   // 32768

#define KNN_BINS  2048
#define KNN_SHIFT 21
#define KNN_PAD   (KNN_BINS + KNN_BINS / 32)
#define HADDR(b)  ((b) + ((b) >> 5))
#define KNN_CAP   384

typedef unsigned short ushort_t;
typedef __attribute__((ext_vector_type(8))) short bf16x8;
typedef __attribute__((ext_vector_type(4))) float f32x4;

__device__ inline unsigned short f2bf(float f) {   // RNE bf16 bits
  unsigned u = __float_as_uint(f);
  return (unsigned short)((u + 0x7FFFu + ((u >> 16) & 1u)) >> 16);
}
__device__ inline float bff(unsigned short h) {
  return __uint_as_float(((unsigned)h) << 16);
}
__device__ inline float2 bf2(unsigned u) {
  return make_float2(__uint_as_float(u << 16), __uint_as_float(u & 0xFFFF0000u));
}

// ---------------------------------------------------------------- prep
__global__ __launch_bounds__(256) void prep_pos4(const float* __restrict__ pos,
                                                 float4* __restrict__ pos4) {
  int i = blockIdx.x * 256 + threadIdx.x;
  float x = pos[i * 3 + 0], y = pos[i * 3 + 1], z = pos[i * 3 + 2];
  pos4[i] = make_float4(x, y, z, x * x + y * y + z * z);
}

// ---------------------------------------------------------------- KNN v8
// r20: phase-A loads batched 8-wide + sched_barrier(0) (r19 attn recipe) —
// the load->use interleave left ~25% issue stall at L2 latency.
__global__ __launch_bounds__(256) void knn_kernel(const float4* __restrict__ pos4,
                                                  int* __restrict__ idxout,
                                                  int tbase) {
  __shared__ __align__(16) unsigned hist[KNN_PAD];
  __shared__ unsigned wsum[4];
  __shared__ unsigned long long cand[KNN_CAP];
  __shared__ unsigned nC, s_bmin;

  int t = tbase + blockIdx.x;
  int b = t >> 12;
  int p = t & (NPTS - 1);
  const float4* base = pos4 + ((size_t)b << 12);
  float4 me = base[p];

  int tid = threadIdx.x;
  int lane = tid & 63, wv = tid >> 6;
#pragma unroll
  for (int i = 0; i < 3; ++i) {
    int w = tid + i * 256;
    if (w < KNN_PAD / 4) ((uint4*)hist)[w] = make_uint4(0u, 0u, 0u, 0u);
  }
  if (tid == 0) nC = 0;
  __syncthreads();

  // ---- phase A: 16 strided diff-form keys, loads batched 8-wide
  unsigned key[16];
  unsigned mn = 0xFFFFFFFFu;
#pragma unroll
  for (int jb = 0; jb < 16; jb += 8) {
    float4 ob[8];
#pragma unroll
    for (int u = 0; u < 8; ++u) ob[u] = base[tid + (jb + u) * 256];
    __builtin_amdgcn_sched_barrier(0);
#pragma unroll
    for (int u = 0; u < 8; ++u) {
      int q = tid + (jb + u) * 256;
      float dx = me.x - ob[u].x, dy = me.y - ob[u].y, dz = me.z - ob[u].z;
      float d2 = dx * dx + dy * dy + dz * dz;   // >= 0: bits monotone
      unsigned k = __float_as_uint(d2);
      key[jb + u] = (q == p) ? 0xFFFFFFFFu : k; // exclude self
      mn = (key[jb + u] < mn) ? key[jb + u] : mn;
    }
  }
  atomicAdd(&hist[HADDR(mn >> KNN_SHIFT)], 1u);
  __syncthreads();

  unsigned s = 0;
#pragma unroll
  for (int i = 0; i < 8; ++i) s += hist[HADDR(tid * 8 + i)];
  unsigned c = s;
#pragma unroll
  for (int d = 1; d < 64; d <<= 1) {
    unsigned x = __shfl_up(c, d);
    if (lane >= d) c += x;
  }
  if (lane == 63) wsum[wv] = c;
  __syncthreads();
  unsigned off = 0;
#pragma unroll
  for (int w = 0; w < 4; ++w) off += (w < wv) ? wsum[w] : 0u;
  unsigned cum_incl = c + off;
  unsigned cum_excl = cum_incl - s;

  if (cum_excl < NBR && cum_incl >= NBR) {
    unsigned h[8];
#pragma unroll
    for (int i = 0; i < 8; ++i) h[i] = hist[HADDR(tid * 8 + i)];
    unsigned c0 = cum_excl; int bin = tid * 8; bool done = false;
#pragma unroll
    for (int i = 0; i < 8; ++i) {
      if (!done) {
        if (c0 + h[i] >= NBR) done = true;
        else { c0 += h[i]; ++bin; }
      }
    }
    s_bmin = (unsigned)bin;
  }
  __syncthreads();
  unsigned kmax = (s_bmin << KNN_SHIFT) | ((1u << KNN_SHIFT) - 1u);

#pragma unroll
  for (int j = 0; j < 16; ++j) {
    if (key[j] <= kmax) {
      int q = tid + j * 256;
      float4 o = base[q];
      float d2r = me.w + o.w - 2.f * (me.x * o.x + me.y * o.y + me.z * o.z);
      unsigned u = __float_as_uint(d2r);
      unsigned fk = u ^ (unsigned)(((int)u >> 31) | 0x80000000);
      unsigned slot = atomicAdd(&nC, 1u);
      if (slot < KNN_CAP)
        cand[slot] = ((unsigned long long)fk << 32) | (unsigned)q;
    }
  }
  __syncthreads();

  int n = (int)(nC < KNN_CAP ? nC : KNN_CAP);
  int* op = idxout + (size_t)t * NBR;
  for (int sidx = tid; sidx < n; sidx += 256) {
    unsigned long long my = cand[sidx];
    int cnt = 0;
    for (int r = 0; r < n; ++r) cnt += (cand[r] < my) ? 1 : 0;
    if (cnt < NBR) op[cnt] = (int)(my & 0xFFFFFFFFu);
  }
}

// ---------------------------------------------------------------- layer-1 algebra
__global__ void l1_pre(const float* __restrict__ wq, const float* __restrict__ bq,
                       const float* __restrict__ wk, const float* __restrict__ bk,
                       float* __restrict__ l1c) {
  int t = threadIdx.x;
  if (t < 9) {
    int a = t / 3, b = t % 3;
    float s = 0.f;
    for (int c = 0; c < 64; ++c) s += wq[a * 64 + c] * wk[b * 64 + c];
    l1c[t] = s;
  } else if (t < 12) {
    int a = t - 9;
    float s = 0.f;
    for (int c = 0; c < 64; ++c) s += wq[a * 64 + c] * bk[c];
    l1c[t] = s;
  } else if (t < 15) {
    int b = t - 12;
    float s = 0.f;
    for (int c = 0; c < 64; ++c) s += wk[b * 64 + c] * bq[c];
    l1c[t] = s;
  } else if (t == 15) {
    float s = 0.f;
    for (int c = 0; c < 64; ++c) s += bq[c] * bk[c];
    l1c[t] = s;
  }
}

__global__ __launch_bounds__(256) void l1_fused(const float4* __restrict__ pos4,
    const int* __restrict__ idx, const float* __restrict__ l1c,
    const float* __restrict__ wvw, const float* __restrict__ bv,
    const float* __restrict__ wsw, const float* __restrict__ bs,
    ushort_t* __restrict__ xsh, ushort_t* __restrict__ xsl) {
  __shared__ float wvs[192], wss[192], bcs[64], cc[16];
  __shared__ float4 pts[16];
  __shared__ int ss[256];
  int tid = threadIdx.x;
  int t0 = blockIdx.x * 16;
  int bofs = (t0 >> 12) << 12;
  if (tid < 192) wvs[tid] = wvw[tid];
  if (tid >= 64) wss[tid - 64] = wsw[tid - 64];
  if (tid < 64) bcs[tid] = bv[tid] + bs[tid];
  if (tid < 16) pts[tid] = pos4[t0 + tid];
  else if (tid >= 16 && tid < 32) cc[tid - 16] = l1c[tid - 16];
  ss[tid] = bofs + idx[t0 * 16 + tid];
  __syncthreads();
  int lane = tid & 63, wq = tid >> 6;
  int tt = lane >> 4, jj = lane & 15;
  int tgt = wq * 4 + tt;
  float4 pj = pos4[ss[tid]];
  float4 pt = pts[tgt];
  float r0 = cc[0] * pj.x + cc[1] * pj.y + cc[2] * pj.z;
  float r1 = cc[3] * pj.x + cc[4] * pj.y + cc[5] * pj.z;
  float r2 = cc[6] * pj.x + cc[7] * pj.y + cc[8] * pj.z;
  float logit = pt.x * (r0 + cc[9]) + pt.y * (r1 + cc[10]) + pt.z * (r2 + cc[11])
              + cc[12] * pj.x + cc[13] * pj.y + cc[14] * pj.z + cc[15];
  logit *= 0.125f;
  float mx = logit;
#pragma unroll
  for (int d = 1; d <= 8; d <<= 1) mx = fmaxf(mx, __shfl_xor(mx, d));
  float e = expf(logit - mx);
  float sm = e;
#pragma unroll
  for (int d = 1; d <= 8; d <<= 1) sm += __shfl_xor(sm, d);
  float a = e / sm;
  float ax = a * pj.x, ay = a * pj.y, az = a * pj.z;
#pragma unroll
  for (int d = 1; d <= 8; d <<= 1) {
    ax += __shfl_xor(ax, d);
    ay += __shfl_xor(ay, d);
    az += __shfl_xor(az, d);
  }
  ushort4 h, l;
  float v0, v1, v2, v3;
  {
    int c = 4 * jj;
    v0 = ax * wvs[c + 0] + ay * wvs[64 + c + 0] + az * wvs[128 + c + 0]
       + pt.x * wss[c + 0] + pt.y * wss[64 + c + 0] + pt.z * wss[128 + c + 0] + bcs[c + 0];
    v1 = ax * wvs[c + 1] + ay * wvs[64 + c + 1] + az * wvs[128 + c + 1]
       + pt.x * wss[c + 1] + pt.y * wss[64 + c + 1] + pt.z * wss[128 + c + 1] + bcs[c + 1];
    v2 = ax * wvs[c + 2] + ay * wvs[64 + c + 2] + az * wvs[128 + c + 2]
       + pt.x * wss[c + 2] + pt.y * wss[64 + c + 2] + pt.z * wss[128 + c + 2] + bcs[c + 2];
    v3 = ax * wvs[c + 3] + ay * wvs[64 + c + 3] + az * wvs[128 + c + 3]
       + pt.x * wss[c + 3] + pt.y * wss[64 + c + 3] + pt.z * wss[128 + c + 3] + bcs[c + 3];
  }
  v0 = fmaxf(v0, 0.f); v1 = fmaxf(v1, 0.f);
  v2 = fmaxf(v2, 0.f); v3 = fmaxf(v3, 0.f);
  h.x = f2bf(v0); l.x = f2bf(v0 - bff(h.x));
  h.y = f2bf(v1); l.y = f2bf(v1 - bff(h.y));
  h.z = f2bf(v2); l.z = f2bf(v2 - bff(h.z));
  h.w = f2bf(v3); l.w = f2bf(v3 - bff(h.w));
  size_t ofs = (size_t)(t0 + tgt) * 64 + 4 * jj;
  *(ushort4*)(xsh + ofs) = h;
  *(ushort4*)(xsl + ofs) = l;
}

// ---------------------------------------------------------------- weight split (4 mats)
template <int K, int SECN>
__global__ __launch_bounds__(256) void split_wt4(const float* __restrict__ w0,
    const float* __restrict__ w1, const float* __restrict__ w2,
    const float* __restrict__ w3,
    ushort_t* __restrict__ th, ushort_t* __restrict__ tl) {
  int i = blockIdx.x * 256 + threadIdx.x;
  if (i >= 4 * K * SECN) return;
  int nm = i / (K * SECN);
  int w = i - nm * (K * SECN);
  int k = w / SECN, n = w - k * SECN;
  const float* wp = (nm == 0) ? w0 : (nm == 1) ? w1 : (nm == 2) ? w2 : w3;
  float v = wp[w];
  unsigned short hh = f2bf(v);
  size_t dst = (size_t)(nm * SECN + n) * K + k;
  th[dst] = hh;
  tl[dst] = f2bf(v - bff(hh));
}

// ---------------------------------------------------------------- combined MFMA GEMM
// r17 canonical LDS-staged K-loop (kept; 364->324 win).
template <int K, int SECN>
__global__ __launch_bounds__(256) void gemm4(const ushort_t* __restrict__ Xh,
    const ushort_t* __restrict__ Xl,
    const ushort_t* __restrict__ Wth, const ushort_t* __restrict__ Wtl,
    const float* __restrict__ bq, const float* __restrict__ bk,
    const float* __restrict__ bv, const float* __restrict__ bs,
    ushort_t* __restrict__ qout, ushort_t* __restrict__ kout,
    ushort_t* __restrict__ vout, float* __restrict__ sout) {
  __shared__ __align__(16) ushort_t tile[4][128 * 40];   // 40 KB
  int lane = threadIdx.x & 63, wv = threadIdx.x >> 6;
  int bm0 = blockIdx.x * 128;
  int gn0 = blockIdx.y * 128;
  int wm = wv >> 1, wn = wv & 1;
  int bm = bm0 + wm * 64;
  int gn = gn0 + wn * 64;
  int r = lane & 15, g4 = lane >> 4;
  f32x4 acc[4][4];
#pragma unroll
  for (int i = 0; i < 4; ++i)
#pragma unroll
    for (int j = 0; j < 4; ++j) acc[i][j] = (f32x4){0.f, 0.f, 0.f, 0.f};

  const ushort_t* sp = (wv == 0) ? Xh : (wv == 1) ? Xl : (wv == 2) ? Wth : Wtl;
  int rbase = (wv < 2) ? bm0 : gn0;
  ushort_t* dst = tile[wv];
  int srow = lane >> 2;          // 0..15
  int skof = (lane & 3) * 8;     // 0,8,16,24 (ushort units)

  for (int k0 = 0; k0 < K; k0 += 32) {
#pragma unroll
    for (int p = 0; p < 8; ++p) {
      int row = p * 16 + srow;
      uint4 v = *(const uint4*)(sp + (size_t)(rbase + row) * K + k0 + skof);
      *(uint4*)&dst[row * 40 + skof] = v;
    }
    __syncthreads();
    bf16x8 ah[4], al[4], bh[4], bl[4];
#pragma unroll
    for (int i = 0; i < 4; ++i) {
      int ra = (wm * 64 + i * 16 + r) * 40 + g4 * 8;
      int rb = (wn * 64 + i * 16 + r) * 40 + g4 * 8;
      ah[i] = *(const bf16x8*)&tile[0][ra];
      al[i] = *(const bf16x8*)&tile[1][ra];
      bh[i] = *(const bf16x8*)&tile[2][rb];
      bl[i] = *(const bf16x8*)&tile[3][rb];
    }
#pragma unroll
    for (int i = 0; i < 4; ++i)
#pragma unroll
      for (int j = 0; j < 4; ++j) {
        acc[i][j] = __builtin_amdgcn_mfma_f32_16x16x32_bf16(ah[i], bh[j], acc[i][j], 0, 0, 0);
        acc[i][j] = __builtin_amdgcn_mfma_f32_16x16x32_bf16(ah[i], bl[j], acc[i][j], 0, 0, 0);
        acc[i][j] = __builtin_amdgcn_mfma_f32_16x16x32_bf16(al[i], bh[j], acc[i][j], 0, 0, 0);
      }
    __syncthreads();
  }

  int sec = gn / SECN;                       // wave-uniform
  int colbase = gn - sec * SECN;
  const float* bp = (sec == 0) ? bq : (sec == 1) ? bk : (sec == 2) ? bv : bs;
  if (sec == 3) {
#pragma unroll
    for (int j = 0; j < 4; ++j) {
      int col = colbase + j * 16 + r;
      float bias = bp[col];
#pragma unroll
      for (int i = 0; i < 4; ++i)
#pragma unroll
        for (int tr = 0; tr < 4; ++tr) {
          int row = bm + i * 16 + g4 * 4 + tr;
          sout[(size_t)row * SECN + col] = acc[i][j][tr] + bias;
        }
    }
  } else {
    ushort_t* outp = (sec == 0) ? qout : (sec == 1) ? kout : vout;
    ushort_t* cw = tile[wv];                 // reuse staging LDS (post-barrier)
#pragma unroll
    for (int half = 0; half < 2; ++half) {
#pragma unroll
      for (int j = 0; j < 4; ++j) {
        int col = j * 16 + r;
        float bias = bp[colbase + col];
#pragma unroll
        for (int i = 0; i < 2; ++i)
#pragma unroll
          for (int tr = 0; tr < 4; ++tr)
            cw[(i * 16 + g4 * 4 + tr) * 72 + col] =
                f2bf(acc[2 * half + i][j][tr] + bias);
      }
#pragma unroll
      for (int it = 0; it < 4; ++it) {
        int row = (lane >> 3) + it * 8;            // 0..31
        int cs = (lane & 7) * 8;
        uint4 v4 = *(uint4*)&cw[row * 72 + cs];    // 8 ushorts = 16 B
        *(uint4*)&outp[(size_t)(bm + half * 32 + row) * SECN + colbase + cs] = v4;
      }
    }
  }
}

// ---------------------------------------------------------------- Attention (bf16 q/k/v)
// XCD batch-affinity swizzle (r9); batched+pinned loads (r19, 323->307 win).
// OUTSPLIT=false: barrier-free per-wave pool partials (r15).
template <int DOUT, bool OUTSPLIT>
__global__ __launch_bounds__(256) void attn_kernel(const ushort_t* __restrict__ qp,
                                                   const ushort_t* __restrict__ kp,
                                                   const ushort_t* __restrict__ vp,
                                                   const int* __restrict__ idx,
                                                   const float* xin,
                                                   void* outa,
                                                   ushort_t* outl,
                                                   float* pbuf) {
  constexpr int F   = DOUT / 4;    // float4 per q row
  constexpr int CPL = DOUT / 16;   // channels per lane in PV
  __shared__ float4 qs[4][4][F + 1];
  __shared__ int    ss[4][64];
  int lane = threadIdx.x & 63, wv = threadIdx.x >> 6;
  int swz = (blockIdx.x & 7) * (MTOT / 16 / 8) + (blockIdx.x >> 3);
  int t0 = swz * 16 + wv * 4;
  int bofs = (t0 >> 12) << 12;
  int tt = lane >> 4, jj = lane & 15;
  int src = bofs + idx[(t0 + tt) * 16 + jj];
  ss[wv][lane] = src;
  const uint4* qp4 = (const uint4*)(qp + (size_t)t0 * DOUT);
#pragma unroll
  for (int i = 0; i < DOUT / 128; ++i) {
    int g = lane + 64 * i;
    uint4 qv = qp4[g];
    int row = g / (DOUT / 8), e8 = g % (DOUT / 8);
    float2 a0 = bf2(qv.x), a1 = bf2(qv.y), a2 = bf2(qv.z), a3 = bf2(qv.w);
    qs[wv][row][2 * e8]     = make_float4(a0.x, a0.y, a1.x, a1.y);
    qs[wv][row][2 * e8 + 1] = make_float4(a2.x, a2.y, a3.x, a3.y);
  }
  __syncthreads();

  // ---- logits: 8 uint4 loads pinned ahead of the FMA cluster
  const uint4* krow = (const uint4*)(kp + (size_t)src * DOUT);
  float accA = 0.f, accB = 0.f;
#pragma unroll
  for (int cb = 0; cb < DOUT / 8; cb += 8) {
    uint4 kb[8];
#pragma unroll
    for (int u = 0; u < 8; ++u) kb[u] = krow[cb + u];
    __builtin_amdgcn_sched_barrier(0);
#pragma unroll
    for (int u = 0; u < 8; ++u) {
      int cch = cb + u;
      float4 q0 = qs[wv][tt][2 * cch], q1 = qs[wv][tt][2 * cch + 1];
      float2 k0 = bf2(kb[u].x), k1 = bf2(kb[u].y);
      float2 k2 = bf2(kb[u].z), k3 = bf2(kb[u].w);
      float d0 = q0.x * k0.x + q0.y * k0.y + q0.z * k1.x + q0.w * k1.y;
      float d1 = q1.x * k2.x + q1.y * k2.y + q1.z * k3.x + q1.w * k3.y;
      if (u & 1) accB += d0 + d1; else accA += d0 + d1;
    }
  }
  float acc = accA + accB;
  const float scale = (DOUT == 128) ? 0.08838834764831843f : 0.0625f;
  float logit = acc * scale;
  float mx = logit;
#pragma unroll
  for (int d = 1; d <= 8; d <<= 1) mx = fmaxf(mx, __shfl_xor(mx, d));
  float e = expf(logit - mx);
  float sm = e;
#pragma unroll
  for (int d = 1; d <= 8; d <<= 1) sm += __shfl_xor(sm, d);
  float a = e / sm;

  // ---- PV: 4 neighbors' v-chunks batched and pinned per step
  float4 o[CPL / 4];
#pragma unroll
  for (int c = 0; c < CPL / 4; ++c) o[c] = make_float4(0.f, 0.f, 0.f, 0.f);
  int gbase = lane & 48;
#pragma unroll
  for (int jb = 0; jb < 16; jb += 4) {
    uint4 vb[4][CPL / 8];
#pragma unroll
    for (int u = 0; u < 4; ++u) {
      const ushort_t* vr = vp + (size_t)ss[wv][gbase | (jb + u)] * DOUT + CPL * jj;
#pragma unroll
      for (int c = 0; c < CPL / 8; ++c) vb[u][c] = ((const uint4*)vr)[c];
    }
    __builtin_amdgcn_sched_barrier(0);
#pragma unroll
    for (int u = 0; u < 4; ++u) {
      float aj = __shfl(a, gbase | (jb + u));
#pragma unroll
      for (int c = 0; c < CPL / 8; ++c) {
        float2 a0 = bf2(vb[u][c].x), a1 = bf2(vb[u][c].y);
        float2 a2 = bf2(vb[u][c].z), a3 = bf2(vb[u][c].w);
        o[2 * c].x += aj * a0.x;     o[2 * c].y += aj * a0.y;
        o[2 * c].z += aj * a1.x;     o[2 * c].w += aj * a1.y;
        o[2 * c + 1].x += aj * a2.x; o[2 * c + 1].y += aj * a2.y;
        o[2 * c + 1].z += aj * a3.x; o[2 * c + 1].w += aj * a3.y;
      }
    }
  }

  size_t chbase = (size_t)(t0 + tt) * DOUT + CPL * jj;
  const float4* xi4 = (const float4*)(xin + chbase);
  float4 rr[CPL / 4];
#pragma unroll
  for (int c = 0; c < CPL / 4; ++c) {
    float4 x4 = xi4[c];
    rr[c].x = fmaxf(x4.x + o[c].x, 0.f);
    rr[c].y = fmaxf(x4.y + o[c].y, 0.f);
    rr[c].z = fmaxf(x4.z + o[c].z, 0.f);
    rr[c].w = fmaxf(x4.w + o[c].w, 0.f);
  }
  if constexpr (OUTSPLIT) {
#pragma unroll
    for (int c = 0; c < CPL / 4; ++c) {
      ushort4 h, l;
      h.x = f2bf(rr[c].x); l.x = f2bf(rr[c].x - bff(h.x));
      h.y = f2bf(rr[c].y); l.y = f2bf(rr[c].y - bff(h.y));
      h.z = f2bf(rr[c].z); l.z = f2bf(rr[c].z - bff(h.z));
      h.w = f2bf(rr[c].w); l.w = f2bf(rr[c].w - bff(h.w));
      *(ushort4*)((ushort_t*)outa + chbase + 4 * c) = h;
      *(ushort4*)(outl + chbase + 4 * c) = l;
    }
  } else {
    // wave-level partial max over its 4 targets; lanes 0-15 store 1KB partial.
#pragma unroll
    for (int c = 0; c < CPL / 4; ++c) {
#pragma unroll
      for (int mask = 16; mask <= 32; mask <<= 1) {
        rr[c].x = fmaxf(rr[c].x, __shfl_xor(rr[c].x, mask));
        rr[c].y = fmaxf(rr[c].y, __shfl_xor(rr[c].y, mask));
        rr[c].z = fmaxf(rr[c].z, __shfl_xor(rr[c].z, mask));
        rr[c].w = fmaxf(rr[c].w, __shfl_xor(rr[c].w, mask));
      }
    }
    if (lane < 16) {   // tt==0, jj==lane: channels CPL*jj .. +CPL
      float4* pb = (float4*)(pbuf + ((size_t)(swz * 4 + wv) * 256) + CPL * jj);
#pragma unroll
      for (int c = 0; c < CPL / 4; ++c) pb[c] = rr[c];
    }
  }
}

// ---------------------------------------------------------------- pool reduce + head
__global__ void zero_kernel(float* g) { g[blockIdx.x * 256 + threadIdx.x] = 0.f; }

__global__ __launch_bounds__(256) void pool_reduce(const float* __restrict__ pbuf,
                                                   float* __restrict__ g) {
  int b = blockIdx.y, s = blockIdx.x, ch = threadIdx.x;
  const float* base = pbuf + ((size_t)b * 1024 + s * 128) * 256 + ch;
  float m = 0.f;
  for (int w = 0; w < 128; ++w) m = fmaxf(m, base[w * 256]);
  atomicMax((int*)&g[b * 256 + ch], __float_as_int(m));  // values >= 0
}

__global__ __launch_bounds__(256) void head_kernel(const float* __restrict__ g,
    const float* __restrict__ w1, const float* __restrict__ b1,
    const float* __restrict__ w2, const float* __restrict__ b2,
    const float* __restrict__ w3, const float* __restrict__ b3,
    float* __restrict__ out) {
  __shared__ float gb[256], h1[512], h2[256], lg[10];
  int b = blockIdx.x, t = threadIdx.x;
  gb[t] = g[b * 256 + t];
  __syncthreads();
#pragma unroll
  for (int half = 0; half < 2; ++half) {
    int c = t + half * 256;
    float a = b1[c];
    for (int kk = 0; kk < 256; ++kk) a += gb[kk] * w1[kk * 512 + c];
    h1[c] = fmaxf(a, 0.f);
  }
  __syncthreads();
  {
    float a = b2[t];
    for (int kk = 0; kk < 512; ++kk) a += h1[kk] * w2[kk * 256 + t];
    h2[t] = fmaxf(a, 0.f);
  }
  __syncthreads();
  if (t < 10) {
    float a = b3[t];
    for (int kk = 0; kk < 256; ++kk) a += h2[kk] * w3[kk * 10 + t];
    lg[t] = a;
  }
  __syncthreads();
  if (t < 10) {
    float mx = lg[0];
#pragma unroll
    for (int i = 1; i < 10; ++i) mx = fmaxf(mx, lg[i]);
    float s = 0.f;
#pragma unroll
    for (int i = 0; i < 10; ++i) s += expf(lg[i] - mx);
    out[b * 10 + t] = lg[t] - mx - logf(s);
  }
}

// ---------------------------------------------------------------- launch
extern "C" void kernel_launch(void* const* d_in, const int* in_sizes, int n_in,
                              void* d_out, int out_size, void* d_ws, size_t ws_size,
                              hipStream_t stream) {
  const float* pos = (const float*)d_in[0];
  const float* W[3][4]; const float* Bb[3][4];
  for (int l = 0; l < 3; ++l)
    for (int nm = 0; nm < 4; ++nm) {           // order q,k,v,s
      W[l][nm]  = (const float*)d_in[1 + l * 8 + nm * 2];
      Bb[l][nm] = (const float*)d_in[1 + l * 8 + nm * 2 + 1];
    }
  const float* fc1w = (const float*)d_in[25]; const float* fc1b = (const float*)d_in[26];
  const float* fc2w = (const float*)d_in[27]; const float* fc2b = (const float*)d_in[28];
  const float* fc3w = (const float*)d_in[29]; const float* fc3b = (const float*)d_in[30];

  int*   idxb  = (int*)d_ws;
  float* fbase = (float*)((char*)d_ws + (size_t)MTOT * NBR * 4);
  float* qb = fbase;
  float* kb = qb + (size_t)MTOT * 256;
  float* vb = kb + (size_t)MTOT * 256;
  float* x2 = vb + (size_t)MTOT * 256;
  float* x3 = x2 + (size_t)MTOT * 128;
  float* g  = x3 + (size_t)MTOT * 256;
  float4* pos4 = (float4*)(g + BATCH * 256);
  ushort_t* xsh = (ushort_t*)(pos4 + MTOT);
  ushort_t* xsl = xsh + (size_t)MTOT * 128;
  ushort_t* th2 = xsl + (size_t)MTOT * 128;
  ushort_t* tl2 = th2 + 512 * 64;
  ushort_t* th3 = tl2 + 512 * 64;
  ushort_t* tl3 = th3 + 1024 * 128;
  float*    l1c = (float*)(tl3 + 1024 * 128);
  float*    pbuf = l1c + 64;                   // 8192 waves x 256 ch = 8MB
  ushort_t* qh = (ushort_t*)qb;
  ushort_t* kh = (ushort_t*)kb;
  ushort_t* vh = (ushort_t*)vb;

  prep_pos4<<<MTOT / 256, 256, 0, stream>>>(pos, pos4);
  knn_kernel<<<MTOT / 2, 256, 0, stream>>>(pos4, idxb, 0);
  knn_kernel<<<MTOT / 2, 256, 0, stream>>>(pos4, idxb, MTOT / 2);

  // layer 1 fused (3x3 quadratic-form attention; exact fp32)
  l1_pre<<<1, 64, 0, stream>>>(W[0][0], Bb[0][0], W[0][1], Bb[0][1], l1c);
  l1_fused<<<MTOT / 16, 256, 0, stream>>>(pos4, idxb, l1c,
                                          W[0][2], Bb[0][2], W[0][3], Bb[0][3],
                                          xsh, xsl);

  // layer 2
  split_wt4<64, 128><<<(4 * 64 * 128 + 255) / 256, 256, 0, stream>>>(
      W[1][0], W[1][1], W[1][2], W[1][3], th2, tl2);
  gemm4<64, 128><<<dim3(MTOT / 128, 4), 256, 0, stream>>>(
      xsh, xsl, th2, tl2, Bb[1][0], Bb[1][1], Bb[1][2], Bb[1][3],
      qh, kh, vh, x2);
  attn_kernel<128, true><<<MTOT / 16, 256, 0, stream>>>(qh, kh, vh, idxb, x2,
                                                        xsh, xsl, nullptr);

  // layer 3 (attention emits per-wave pool partials; reduce after)
  split_wt4<128, 256><<<(4 * 128 * 256 + 255) / 256, 256, 0, stream>>>(
      W[2][0], W[2][1], W[2][2], W[2][3], th3, tl3);
  gemm4<128, 256><<<dim3(MTOT / 128, 8), 256, 0, stream>>>(
      xsh, xsl, th3, tl3, Bb[2][0], Bb[2][1], Bb[2][2], Bb[2][3],
      qh, kh, vh, x3);
  attn_kernel<256, false><<<MTOT / 16, 256, 0, stream>>>(qh, kh, vh, idxb, x3,
                                                         nullptr, nullptr, pbuf);

  // pool reduce + MLP head
  zero_kernel<<<8, 256, 0, stream>>>(g);
  pool_reduce<<<dim3(8, 8), 256, 0, stream>>>(pbuf, g);
  head_kernel<<<8, 256, 0, stream>>>(g, fc1w, fc1b, fc2w, fc2b, fc3w, fc3b,
                                     (float*)d_out);
}

// Round 22
// 301.675 us; speedup vs baseline: 1.0499x; 1.0499x over previous
//
#include <hip/hip_runtime.h>
#include <math.h>

#define BATCH 8
#define NPTS  4096
#define NBR   16
#define MTOT  (BATCH * NPTS)   // 32768

#define KNN_BINS  2048
#define KNN_SHIFT 21
#define KNN_PAD   (KNN_BINS + KNN_BINS / 32)
#define HADDR(b)  ((b) + ((b) >> 5))
#define KNN_CAP   384

typedef unsigned short ushort_t;
typedef __attribute__((ext_vector_type(8))) short bf16x8;
typedef __attribute__((ext_vector_type(4))) float f32x4;

__device__ inline unsigned short f2bf(float f) {   // RNE bf16 bits
  unsigned u = __float_as_uint(f);
  return (unsigned short)((u + 0x7FFFu + ((u >> 16) & 1u)) >> 16);
}
__device__ inline float bff(unsigned short h) {
  return __uint_as_float(((unsigned)h) << 16);
}
__device__ inline float2 bf2(unsigned u) {
  return make_float2(__uint_as_float(u << 16), __uint_as_float(u & 0xFFFF0000u));
}

// ---------------------------------------------------------------- prep
__global__ __launch_bounds__(256) void prep_pos4(const float* __restrict__ pos,
                                                 float4* __restrict__ pos4) {
  int i = blockIdx.x * 256 + threadIdx.x;
  float x = pos[i * 3 + 0], y = pos[i * 3 + 1], z = pos[i * 3 + 2];
  pos4[i] = make_float4(x, y, z, x * x + y * y + z * z);
}

// ---------------------------------------------------------------- KNN v7 (final)
// One block = one target; 16 strided candidates/thread (wave-coalesced).
// Thread-minima histogram select (r6 proof); survivors -> exact reference
// keys; rank-by-counting emit. r21: r20's load-batching REVERTED — knn is
// issue-bound (76% VALUBusy), the fence only cost scheduler freedom (-4.5us).
__global__ __launch_bounds__(256) void knn_kernel(const float4* __restrict__ pos4,
                                                  int* __restrict__ idxout) {
  __shared__ __align__(16) unsigned hist[KNN_PAD];
  __shared__ unsigned wsum[4];
  __shared__ unsigned long long cand[KNN_CAP];
  __shared__ unsigned nC, s_bmin;

  int t = blockIdx.x;
  int b = t >> 12;
  int p = t & (NPTS - 1);
  const float4* base = pos4 + ((size_t)b << 12);
  float4 me = base[p];

  int tid = threadIdx.x;
  int lane = tid & 63, wv = tid >> 6;
#pragma unroll
  for (int i = 0; i < 3; ++i) {
    int w = tid + i * 256;
    if (w < KNN_PAD / 4) ((uint4*)hist)[w] = make_uint4(0u, 0u, 0u, 0u);
  }
  if (tid == 0) nC = 0;
  __syncthreads();

  unsigned key[16];
  unsigned mn = 0xFFFFFFFFu;
#pragma unroll
  for (int j = 0; j < 16; ++j) {
    int q = tid + j * 256;
    float4 o = base[q];
    float dx = me.x - o.x, dy = me.y - o.y, dz = me.z - o.z;
    float d2 = dx * dx + dy * dy + dz * dz;   // >= 0: bits monotone
    unsigned k = __float_as_uint(d2);
    key[j] = (q == p) ? 0xFFFFFFFFu : k;      // exclude self
    mn = (key[j] < mn) ? key[j] : mn;
  }
  atomicAdd(&hist[HADDR(mn >> KNN_SHIFT)], 1u);
  __syncthreads();

  unsigned s = 0;
#pragma unroll
  for (int i = 0; i < 8; ++i) s += hist[HADDR(tid * 8 + i)];
  unsigned c = s;
#pragma unroll
  for (int d = 1; d < 64; d <<= 1) {
    unsigned x = __shfl_up(c, d);
    if (lane >= d) c += x;
  }
  if (lane == 63) wsum[wv] = c;
  __syncthreads();
  unsigned off = 0;
#pragma unroll
  for (int w = 0; w < 4; ++w) off += (w < wv) ? wsum[w] : 0u;
  unsigned cum_incl = c + off;
  unsigned cum_excl = cum_incl - s;

  if (cum_excl < NBR && cum_incl >= NBR) {
    unsigned h[8];
#pragma unroll
    for (int i = 0; i < 8; ++i) h[i] = hist[HADDR(tid * 8 + i)];
    unsigned c0 = cum_excl; int bin = tid * 8; bool done = false;
#pragma unroll
    for (int i = 0; i < 8; ++i) {
      if (!done) {
        if (c0 + h[i] >= NBR) done = true;
        else { c0 += h[i]; ++bin; }
      }
    }
    s_bmin = (unsigned)bin;
  }
  __syncthreads();
  unsigned kmax = (s_bmin << KNN_SHIFT) | ((1u << KNN_SHIFT) - 1u);

#pragma unroll
  for (int j = 0; j < 16; ++j) {
    if (key[j] <= kmax) {
      int q = tid + j * 256;
      float4 o = base[q];
      float d2r = me.w + o.w - 2.f * (me.x * o.x + me.y * o.y + me.z * o.z);
      unsigned u = __float_as_uint(d2r);
      unsigned fk = u ^ (unsigned)(((int)u >> 31) | 0x80000000);
      unsigned slot = atomicAdd(&nC, 1u);
      if (slot < KNN_CAP)
        cand[slot] = ((unsigned long long)fk << 32) | (unsigned)q;
    }
  }
  __syncthreads();

  int n = (int)(nC < KNN_CAP ? nC : KNN_CAP);
  int* op = idxout + (size_t)t * NBR;
  for (int sidx = tid; sidx < n; sidx += 256) {
    unsigned long long my = cand[sidx];
    int cnt = 0;
    for (int r = 0; r < n; ++r) cnt += (cand[r] < my) ? 1 : 0;
    if (cnt < NBR) op[cnt] = (int)(my & 0xFFFFFFFFu);
  }
}

// ---------------------------------------------------------------- layer-1 algebra
__global__ void l1_pre(const float* __restrict__ wq, const float* __restrict__ bq,
                       const float* __restrict__ wk, const float* __restrict__ bk,
                       float* __restrict__ l1c) {
  int t = threadIdx.x;
  if (t < 9) {
    int a = t / 3, b = t % 3;
    float s = 0.f;
    for (int c = 0; c < 64; ++c) s += wq[a * 64 + c] * wk[b * 64 + c];
    l1c[t] = s;
  } else if (t < 12) {
    int a = t - 9;
    float s = 0.f;
    for (int c = 0; c < 64; ++c) s += wq[a * 64 + c] * bk[c];
    l1c[t] = s;
  } else if (t < 15) {
    int b = t - 12;
    float s = 0.f;
    for (int c = 0; c < 64; ++c) s += wk[b * 64 + c] * bq[c];
    l1c[t] = s;
  } else if (t == 15) {
    float s = 0.f;
    for (int c = 0; c < 64; ++c) s += bq[c] * bk[c];
    l1c[t] = s;
  }
}

__global__ __launch_bounds__(256) void l1_fused(const float4* __restrict__ pos4,
    const int* __restrict__ idx, const float* __restrict__ l1c,
    const float* __restrict__ wvw, const float* __restrict__ bv,
    const float* __restrict__ wsw, const float* __restrict__ bs,
    ushort_t* __restrict__ xsh, ushort_t* __restrict__ xsl) {
  __shared__ float wvs[192], wss[192], bcs[64], cc[16];
  __shared__ float4 pts[16];
  __shared__ int ss[256];
  int tid = threadIdx.x;
  int t0 = blockIdx.x * 16;
  int bofs = (t0 >> 12) << 12;
  if (tid < 192) wvs[tid] = wvw[tid];
  if (tid >= 64) wss[tid - 64] = wsw[tid - 64];
  if (tid < 64) bcs[tid] = bv[tid] + bs[tid];
  if (tid < 16) pts[tid] = pos4[t0 + tid];
  else if (tid >= 16 && tid < 32) cc[tid - 16] = l1c[tid - 16];
  ss[tid] = bofs + idx[t0 * 16 + tid];
  __syncthreads();
  int lane = tid & 63, wq = tid >> 6;
  int tt = lane >> 4, jj = lane & 15;
  int tgt = wq * 4 + tt;
  float4 pj = pos4[ss[tid]];
  float4 pt = pts[tgt];
  float r0 = cc[0] * pj.x + cc[1] * pj.y + cc[2] * pj.z;
  float r1 = cc[3] * pj.x + cc[4] * pj.y + cc[5] * pj.z;
  float r2 = cc[6] * pj.x + cc[7] * pj.y + cc[8] * pj.z;
  float logit = pt.x * (r0 + cc[9]) + pt.y * (r1 + cc[10]) + pt.z * (r2 + cc[11])
              + cc[12] * pj.x + cc[13] * pj.y + cc[14] * pj.z + cc[15];
  logit *= 0.125f;
  float mx = logit;
#pragma unroll
  for (int d = 1; d <= 8; d <<= 1) mx = fmaxf(mx, __shfl_xor(mx, d));
  float e = expf(logit - mx);
  float sm = e;
#pragma unroll
  for (int d = 1; d <= 8; d <<= 1) sm += __shfl_xor(sm, d);
  float a = e / sm;
  float ax = a * pj.x, ay = a * pj.y, az = a * pj.z;
#pragma unroll
  for (int d = 1; d <= 8; d <<= 1) {
    ax += __shfl_xor(ax, d);
    ay += __shfl_xor(ay, d);
    az += __shfl_xor(az, d);
  }
  ushort4 h, l;
  float v0, v1, v2, v3;
  {
    int c = 4 * jj;
    v0 = ax * wvs[c + 0] + ay * wvs[64 + c + 0] + az * wvs[128 + c + 0]
       + pt.x * wss[c + 0] + pt.y * wss[64 + c + 0] + pt.z * wss[128 + c + 0] + bcs[c + 0];
    v1 = ax * wvs[c + 1] + ay * wvs[64 + c + 1] + az * wvs[128 + c + 1]
       + pt.x * wss[c + 1] + pt.y * wss[64 + c + 1] + pt.z * wss[128 + c + 1] + bcs[c + 1];
    v2 = ax * wvs[c + 2] + ay * wvs[64 + c + 2] + az * wvs[128 + c + 2]
       + pt.x * wss[c + 2] + pt.y * wss[64 + c + 2] + pt.z * wss[128 + c + 2] + bcs[c + 2];
    v3 = ax * wvs[c + 3] + ay * wvs[64 + c + 3] + az * wvs[128 + c + 3]
       + pt.x * wss[c + 3] + pt.y * wss[64 + c + 3] + pt.z * wss[128 + c + 3] + bcs[c + 3];
  }
  v0 = fmaxf(v0, 0.f); v1 = fmaxf(v1, 0.f);
  v2 = fmaxf(v2, 0.f); v3 = fmaxf(v3, 0.f);
  h.x = f2bf(v0); l.x = f2bf(v0 - bff(h.x));
  h.y = f2bf(v1); l.y = f2bf(v1 - bff(h.y));
  h.z = f2bf(v2); l.z = f2bf(v2 - bff(h.z));
  h.w = f2bf(v3); l.w = f2bf(v3 - bff(h.w));
  size_t ofs = (size_t)(t0 + tgt) * 64 + 4 * jj;
  *(ushort4*)(xsh + ofs) = h;
  *(ushort4*)(xsl + ofs) = l;
}

// ---------------------------------------------------------------- weight split (4 mats)
template <int K, int SECN>
__global__ __launch_bounds__(256) void split_wt4(const float* __restrict__ w0,
    const float* __restrict__ w1, const float* __restrict__ w2,
    const float* __restrict__ w3,
    ushort_t* __restrict__ th, ushort_t* __restrict__ tl) {
  int i = blockIdx.x * 256 + threadIdx.x;
  if (i >= 4 * K * SECN) return;
  int nm = i / (K * SECN);
  int w = i - nm * (K * SECN);
  int k = w / SECN, n = w - k * SECN;
  const float* wp = (nm == 0) ? w0 : (nm == 1) ? w1 : (nm == 2) ? w2 : w3;
  float v = wp[w];
  unsigned short hh = f2bf(v);
  size_t dst = (size_t)(nm * SECN + n) * K + k;
  th[dst] = hh;
  tl[dst] = f2bf(v - bff(hh));
}

// ---------------------------------------------------------------- combined MFMA GEMM
// r17 canonical LDS-staged K-loop (kept; 364->324 win).
template <int K, int SECN>
__global__ __launch_bounds__(256) void gemm4(const ushort_t* __restrict__ Xh,
    const ushort_t* __restrict__ Xl,
    const ushort_t* __restrict__ Wth, const ushort_t* __restrict__ Wtl,
    const float* __restrict__ bq, const float* __restrict__ bk,
    const float* __restrict__ bv, const float* __restrict__ bs,
    ushort_t* __restrict__ qout, ushort_t* __restrict__ kout,
    ushort_t* __restrict__ vout, float* __restrict__ sout) {
  __shared__ __align__(16) ushort_t tile[4][128 * 40];   // 40 KB
  int lane = threadIdx.x & 63, wv = threadIdx.x >> 6;
  int bm0 = blockIdx.x * 128;
  int gn0 = blockIdx.y * 128;
  int wm = wv >> 1, wn = wv & 1;
  int bm = bm0 + wm * 64;
  int gn = gn0 + wn * 64;
  int r = lane & 15, g4 = lane >> 4;
  f32x4 acc[4][4];
#pragma unroll
  for (int i = 0; i < 4; ++i)
#pragma unroll
    for (int j = 0; j < 4; ++j) acc[i][j] = (f32x4){0.f, 0.f, 0.f, 0.f};

  const ushort_t* sp = (wv == 0) ? Xh : (wv == 1) ? Xl : (wv == 2) ? Wth : Wtl;
  int rbase = (wv < 2) ? bm0 : gn0;
  ushort_t* dst = tile[wv];
  int srow = lane >> 2;          // 0..15
  int skof = (lane & 3) * 8;     // 0,8,16,24 (ushort units)

  for (int k0 = 0; k0 < K; k0 += 32) {
#pragma unroll
    for (int p = 0; p < 8; ++p) {
      int row = p * 16 + srow;
      uint4 v = *(const uint4*)(sp + (size_t)(rbase + row) * K + k0 + skof);
      *(uint4*)&dst[row * 40 + skof] = v;
    }
    __syncthreads();
    bf16x8 ah[4], al[4], bh[4], bl[4];
#pragma unroll
    for (int i = 0; i < 4; ++i) {
      int ra = (wm * 64 + i * 16 + r) * 40 + g4 * 8;
      int rb = (wn * 64 + i * 16 + r) * 40 + g4 * 8;
      ah[i] = *(const bf16x8*)&tile[0][ra];
      al[i] = *(const bf16x8*)&tile[1][ra];
      bh[i] = *(const bf16x8*)&tile[2][rb];
      bl[i] = *(const bf16x8*)&tile[3][rb];
    }
#pragma unroll
    for (int i = 0; i < 4; ++i)
#pragma unroll
      for (int j = 0; j < 4; ++j) {
        acc[i][j] = __builtin_amdgcn_mfma_f32_16x16x32_bf16(ah[i], bh[j], acc[i][j], 0, 0, 0);
        acc[i][j] = __builtin_amdgcn_mfma_f32_16x16x32_bf16(ah[i], bl[j], acc[i][j], 0, 0, 0);
        acc[i][j] = __builtin_amdgcn_mfma_f32_16x16x32_bf16(al[i], bh[j], acc[i][j], 0, 0, 0);
      }
    __syncthreads();
  }

  int sec = gn / SECN;                       // wave-uniform
  int colbase = gn - sec * SECN;
  const float* bp = (sec == 0) ? bq : (sec == 1) ? bk : (sec == 2) ? bv : bs;
  if (sec == 3) {
#pragma unroll
    for (int j = 0; j < 4; ++j) {
      int col = colbase + j * 16 + r;
      float bias = bp[col];
#pragma unroll
      for (int i = 0; i < 4; ++i)
#pragma unroll
        for (int tr = 0; tr < 4; ++tr) {
          int row = bm + i * 16 + g4 * 4 + tr;
          sout[(size_t)row * SECN + col] = acc[i][j][tr] + bias;
        }
    }
  } else {
    ushort_t* outp = (sec == 0) ? qout : (sec == 1) ? kout : vout;
    ushort_t* cw = tile[wv];                 // reuse staging LDS (post-barrier)
#pragma unroll
    for (int half = 0; half < 2; ++half) {
#pragma unroll
      for (int j = 0; j < 4; ++j) {
        int col = j * 16 + r;
        float bias = bp[colbase + col];
#pragma unroll
        for (int i = 0; i < 2; ++i)
#pragma unroll
          for (int tr = 0; tr < 4; ++tr)
            cw[(i * 16 + g4 * 4 + tr) * 72 + col] =
                f2bf(acc[2 * half + i][j][tr] + bias);
      }
#pragma unroll
      for (int it = 0; it < 4; ++it) {
        int row = (lane >> 3) + it * 8;            // 0..31
        int cs = (lane & 7) * 8;
        uint4 v4 = *(uint4*)&cw[row * 72 + cs];    // 8 ushorts = 16 B
        *(uint4*)&outp[(size_t)(bm + half * 32 + row) * SECN + colbase + cs] = v4;
      }
    }
  }
}

// ---------------------------------------------------------------- Attention (bf16 q/k/v)
// XCD batch-affinity swizzle (r9); batched+pinned loads (r19, 323->307 win —
// attn was LATENCY-bound, so the fence pays here, unlike knn).
// OUTSPLIT=false: barrier-free per-wave pool partials (r15).
template <int DOUT, bool OUTSPLIT>
__global__ __launch_bounds__(256) void attn_kernel(const ushort_t* __restrict__ qp,
                                                   const ushort_t* __restrict__ kp,
                                                   const ushort_t* __restrict__ vp,
                                                   const int* __restrict__ idx,
                                                   const float* xin,
                                                   void* outa,
                                                   ushort_t* outl,
                                                   float* pbuf) {
  constexpr int F   = DOUT / 4;    // float4 per q row
  constexpr int CPL = DOUT / 16;   // channels per lane in PV
  __shared__ float4 qs[4][4][F + 1];
  __shared__ int    ss[4][64];
  int lane = threadIdx.x & 63, wv = threadIdx.x >> 6;
  int swz = (blockIdx.x & 7) * (MTOT / 16 / 8) + (blockIdx.x >> 3);
  int t0 = swz * 16 + wv * 4;
  int bofs = (t0 >> 12) << 12;
  int tt = lane >> 4, jj = lane & 15;
  int src = bofs + idx[(t0 + tt) * 16 + jj];
  ss[wv][lane] = src;
  const uint4* qp4 = (const uint4*)(qp + (size_t)t0 * DOUT);
#pragma unroll
  for (int i = 0; i < DOUT / 128; ++i) {
    int g = lane + 64 * i;
    uint4 qv = qp4[g];
    int row = g / (DOUT / 8), e8 = g % (DOUT / 8);
    float2 a0 = bf2(qv.x), a1 = bf2(qv.y), a2 = bf2(qv.z), a3 = bf2(qv.w);
    qs[wv][row][2 * e8]     = make_float4(a0.x, a0.y, a1.x, a1.y);
    qs[wv][row][2 * e8 + 1] = make_float4(a2.x, a2.y, a3.x, a3.y);
  }
  __syncthreads();

  // ---- logits: 8 uint4 loads pinned ahead of the FMA cluster
  const uint4* krow = (const uint4*)(kp + (size_t)src * DOUT);
  float accA = 0.f, accB = 0.f;
#pragma unroll
  for (int cb = 0; cb < DOUT / 8; cb += 8) {
    uint4 kb[8];
#pragma unroll
    for (int u = 0; u < 8; ++u) kb[u] = krow[cb + u];
    __builtin_amdgcn_sched_barrier(0);
#pragma unroll
    for (int u = 0; u < 8; ++u) {
      int cch = cb + u;
      float4 q0 = qs[wv][tt][2 * cch], q1 = qs[wv][tt][2 * cch + 1];
      float2 k0 = bf2(kb[u].x), k1 = bf2(kb[u].y);
      float2 k2 = bf2(kb[u].z), k3 = bf2(kb[u].w);
      float d0 = q0.x * k0.x + q0.y * k0.y + q0.z * k1.x + q0.w * k1.y;
      float d1 = q1.x * k2.x + q1.y * k2.y + q1.z * k3.x + q1.w * k3.y;
      if (u & 1) accB += d0 + d1; else accA += d0 + d1;
    }
  }
  float acc = accA + accB;
  const float scale = (DOUT == 128) ? 0.08838834764831843f : 0.0625f;
  float logit = acc * scale;
  float mx = logit;
#pragma unroll
  for (int d = 1; d <= 8; d <<= 1) mx = fmaxf(mx, __shfl_xor(mx, d));
  float e = expf(logit - mx);
  float sm = e;
#pragma unroll
  for (int d = 1; d <= 8; d <<= 1) sm += __shfl_xor(sm, d);
  float a = e / sm;

  // ---- PV: 4 neighbors' v-chunks batched and pinned per step
  float4 o[CPL / 4];
#pragma unroll
  for (int c = 0; c < CPL / 4; ++c) o[c] = make_float4(0.f, 0.f, 0.f, 0.f);
  int gbase = lane & 48;
#pragma unroll
  for (int jb = 0; jb < 16; jb += 4) {
    uint4 vb[4][CPL / 8];
#pragma unroll
    for (int u = 0; u < 4; ++u) {
      const ushort_t* vr = vp + (size_t)ss[wv][gbase | (jb + u)] * DOUT + CPL * jj;
#pragma unroll
      for (int c = 0; c < CPL / 8; ++c) vb[u][c] = ((const uint4*)vr)[c];
    }
    __builtin_amdgcn_sched_barrier(0);
#pragma unroll
    for (int u = 0; u < 4; ++u) {
      float aj = __shfl(a, gbase | (jb + u));
#pragma unroll
      for (int c = 0; c < CPL / 8; ++c) {
        float2 a0 = bf2(vb[u][c].x), a1 = bf2(vb[u][c].y);
        float2 a2 = bf2(vb[u][c].z), a3 = bf2(vb[u][c].w);
        o[2 * c].x += aj * a0.x;     o[2 * c].y += aj * a0.y;
        o[2 * c].z += aj * a1.x;     o[2 * c].w += aj * a1.y;
        o[2 * c + 1].x += aj * a2.x; o[2 * c + 1].y += aj * a2.y;
        o[2 * c + 1].z += aj * a3.x; o[2 * c + 1].w += aj * a3.y;
      }
    }
  }

  size_t chbase = (size_t)(t0 + tt) * DOUT + CPL * jj;
  const float4* xi4 = (const float4*)(xin + chbase);
  float4 rr[CPL / 4];
#pragma unroll
  for (int c = 0; c < CPL / 4; ++c) {
    float4 x4 = xi4[c];
    rr[c].x = fmaxf(x4.x + o[c].x, 0.f);
    rr[c].y = fmaxf(x4.y + o[c].y, 0.f);
    rr[c].z = fmaxf(x4.z + o[c].z, 0.f);
    rr[c].w = fmaxf(x4.w + o[c].w, 0.f);
  }
  if constexpr (OUTSPLIT) {
#pragma unroll
    for (int c = 0; c < CPL / 4; ++c) {
      ushort4 h, l;
      h.x = f2bf(rr[c].x); l.x = f2bf(rr[c].x - bff(h.x));
      h.y = f2bf(rr[c].y); l.y = f2bf(rr[c].y - bff(h.y));
      h.z = f2bf(rr[c].z); l.z = f2bf(rr[c].z - bff(h.z));
      h.w = f2bf(rr[c].w); l.w = f2bf(rr[c].w - bff(h.w));
      *(ushort4*)((ushort_t*)outa + chbase + 4 * c) = h;
      *(ushort4*)(outl + chbase + 4 * c) = l;
    }
  } else {
    // wave-level partial max over its 4 targets; lanes 0-15 store 1KB partial.
#pragma unroll
    for (int c = 0; c < CPL / 4; ++c) {
#pragma unroll
      for (int mask = 16; mask <= 32; mask <<= 1) {
        rr[c].x = fmaxf(rr[c].x, __shfl_xor(rr[c].x, mask));
        rr[c].y = fmaxf(rr[c].y, __shfl_xor(rr[c].y, mask));
        rr[c].z = fmaxf(rr[c].z, __shfl_xor(rr[c].z, mask));
        rr[c].w = fmaxf(rr[c].w, __shfl_xor(rr[c].w, mask));
      }
    }
    if (lane < 16) {   // tt==0, jj==lane: channels CPL*jj .. +CPL
      float4* pb = (float4*)(pbuf + ((size_t)(swz * 4 + wv) * 256) + CPL * jj);
#pragma unroll
      for (int c = 0; c < CPL / 4; ++c) pb[c] = rr[c];
    }
  }
}

// ---------------------------------------------------------------- pool reduce + head
__global__ void zero_kernel(float* g) { g[blockIdx.x * 256 + threadIdx.x] = 0.f; }

__global__ __launch_bounds__(256) void pool_reduce(const float* __restrict__ pbuf,
                                                   float* __restrict__ g) {
  int b = blockIdx.y, s = blockIdx.x, ch = threadIdx.x;
  const float* base = pbuf + ((size_t)b * 1024 + s * 128) * 256 + ch;
  float m = 0.f;
  for (int w = 0; w < 128; ++w) m = fmaxf(m, base[w * 256]);
  atomicMax((int*)&g[b * 256 + ch], __float_as_int(m));  // values >= 0
}

__global__ __launch_bounds__(256) void head_kernel(const float* __restrict__ g,
    const float* __restrict__ w1, const float* __restrict__ b1,
    const float* __restrict__ w2, const float* __restrict__ b2,
    const float* __restrict__ w3, const float* __restrict__ b3,
    float* __restrict__ out) {
  __shared__ float gb[256], h1[512], h2[256], lg[10];
  int b = blockIdx.x, t = threadIdx.x;
  gb[t] = g[b * 256 + t];
  __syncthreads();
#pragma unroll
  for (int half = 0; half < 2; ++half) {
    int c = t + half * 256;
    float a = b1[c];
    for (int kk = 0; kk < 256; ++kk) a += gb[kk] * w1[kk * 512 + c];
    h1[c] = fmaxf(a, 0.f);
  }
  __syncthreads();
  {
    float a = b2[t];
    for (int kk = 0; kk < 512; ++kk) a += h1[kk] * w2[kk * 256 + t];
    h2[t] = fmaxf(a, 0.f);
  }
  __syncthreads();
  if (t < 10) {
    float a = b3[t];
    for (int kk = 0; kk < 256; ++kk) a += h2[kk] * w3[kk * 10 + t];
    lg[t] = a;
  }
  __syncthreads();
  if (t < 10) {
    float mx = lg[0];
#pragma unroll
    for (int i = 1; i < 10; ++i) mx = fmaxf(mx, lg[i]);
    float s = 0.f;
#pragma unroll
    for (int i = 0; i < 10; ++i) s += expf(lg[i] - mx);
    out[b * 10 + t] = lg[t] - mx - logf(s);
  }
}

// ---------------------------------------------------------------- launch
extern "C" void kernel_launch(void* const* d_in, const int* in_sizes, int n_in,
                              void* d_out, int out_size, void* d_ws, size_t ws_size,
                              hipStream_t stream) {
  const float* pos = (const float*)d_in[0];
  const float* W[3][4]; const float* Bb[3][4];
  for (int l = 0; l < 3; ++l)
    for (int nm = 0; nm < 4; ++nm) {           // order q,k,v,s
      W[l][nm]  = (const float*)d_in[1 + l * 8 + nm * 2];
      Bb[l][nm] = (const float*)d_in[1 + l * 8 + nm * 2 + 1];
    }
  const float* fc1w = (const float*)d_in[25]; const float* fc1b = (const float*)d_in[26];
  const float* fc2w = (const float*)d_in[27]; const float* fc2b = (const float*)d_in[28];
  const float* fc3w = (const float*)d_in[29]; const float* fc3b = (const float*)d_in[30];

  int*   idxb  = (int*)d_ws;
  float* fbase = (float*)((char*)d_ws + (size_t)MTOT * NBR * 4);
  float* qb = fbase;
  float* kb = qb + (size_t)MTOT * 256;
  float* vb = kb + (size_t)MTOT * 256;
  float* x2 = vb + (size_t)MTOT * 256;
  float* x3 = x2 + (size_t)MTOT * 128;
  float* g  = x3 + (size_t)MTOT * 256;
  float4* pos4 = (float4*)(g + BATCH * 256);
  ushort_t* xsh = (ushort_t*)(pos4 + MTOT);
  ushort_t* xsl = xsh + (size_t)MTOT * 128;
  ushort_t* th2 = xsl + (size_t)MTOT * 128;
  ushort_t* tl2 = th2 + 512 * 64;
  ushort_t* th3 = tl2 + 512 * 64;
  ushort_t* tl3 = th3 + 1024 * 128;
  float*    l1c = (float*)(tl3 + 1024 * 128);
  float*    pbuf = l1c + 64;                   // 8192 waves x 256 ch = 8MB
  ushort_t* qh = (ushort_t*)qb;
  ushort_t* kh = (ushort_t*)kb;
  ushort_t* vh = (ushort_t*)vb;

  prep_pos4<<<MTOT / 256, 256, 0, stream>>>(pos, pos4);
  knn_kernel<<<MTOT, 256, 0, stream>>>(pos4, idxb);

  // layer 1 fused (3x3 quadratic-form attention; exact fp32)
  l1_pre<<<1, 64, 0, stream>>>(W[0][0], Bb[0][0], W[0][1], Bb[0][1], l1c);
  l1_fused<<<MTOT / 16, 256, 0, stream>>>(pos4, idxb, l1c,
                                          W[0][2], Bb[0][2], W[0][3], Bb[0][3],
                                          xsh, xsl);

  // layer 2
  split_wt4<64, 128><<<(4 * 64 * 128 + 255) / 256, 256, 0, stream>>>(
      W[1][0], W[1][1], W[1][2], W[1][3], th2, tl2);
  gemm4<64, 128><<<dim3(MTOT / 128, 4), 256, 0, stream>>>(
      xsh, xsl, th2, tl2, Bb[1][0], Bb[1][1], Bb[1][2], Bb[1][3],
      qh, kh, vh, x2);
  attn_kernel<128, true><<<MTOT / 16, 256, 0, stream>>>(qh, kh, vh, idxb, x2,
                                                        xsh, xsl, nullptr);

  // layer 3 (attention emits per-wave pool partials; reduce after)
  split_wt4<128, 256><<<(4 * 128 * 256 + 255) / 256, 256, 0, stream>>>(
      W[2][0], W[2][1], W[2][2], W[2][3], th3, tl3);
  gemm4<128, 256><<<dim3(MTOT / 128, 8), 256, 0, stream>>>(
      xsh, xsl, th3, tl3, Bb[2][0], Bb[2][1], Bb[2][2], Bb[2][3],
      qh, kh, vh, x3);
  attn_kernel<256, false><<<MTOT / 16, 256, 0, stream>>>(qh, kh, vh, idxb, x3,
                                                         nullptr, nullptr, pbuf);

  // pool reduce + MLP head
  zero_kernel<<<8, 256, 0, stream>>>(g);
  pool_reduce<<<dim3(8, 8), 256, 0, stream>>>(pbuf, g);
  head_kernel<<<8, 256, 0, stream>>>(g, fc1w, fc1b, fc2w, fc2b, fc3w, fc3b,
                                     (float*)d_out);
}